// Round 7
// baseline (511.502 us; speedup 1.0000x reference)
//
#include <hip/hip_runtime.h>
#include <hip/hip_cooperative_groups.h>
#include <math.h>

namespace cg = cooperative_groups;

#define B_ 8
#define N_ 2048
#define D_ 512
#define NROWS (B_ * N_)
#define NEG_ALPHA 0.1f

typedef __bf16 bf16;
typedef __bf16 bf16x4 __attribute__((ext_vector_type(4)));
typedef __bf16 bf16x8 __attribute__((ext_vector_type(8)));
typedef float f32x4 __attribute__((ext_vector_type(4)));
typedef float f32x16 __attribute__((ext_vector_type(16)));

// HtB layout (per batch, 2 MB): chunk c = (d>>5)*(N_/16) + (j>>4); chunk =
// 64 lanes x 8 bf16; (l,e) <-> d = (c_d)*32 + (l&31), j = (c_j)*16 + (l>>5)*8 + e.
// Exactly the mfma_32x32x16 B-fragment order.
#define HTB_BATCH ((D_ / 32) * (N_ / 16) * 512)  // 2 MB

// WtB layout: chunk c = db*32 + kc (db: dout-block of 32, kc: din-chunk of 16);
// element (l,e) <-> dout = db*32 + (l&31), din = kc*16 + (l>>5)*8 + e.
#define WTB_CHUNKS ((D_ / 32) * (D_ / 16))  // 512 chunks = 0.5 MB

#define XS_PITCH 520  // bf16 elems; rows 1040 B -> 16B-aligned, 4-way banks
#define AT_BK 32
#define NIT (N_ / AT_BK)  // 64
#define LDP 40
#define GROW 272

__global__ __launch_bounds__(512, 1) void k_fused(
    const float* __restrict__ X, const int* __restrict__ G,
    const float* __restrict__ W, const float* __restrict__ a1,
    const float* __restrict__ a2, float* __restrict__ wa1g,
    float* __restrict__ wa2g, bf16* __restrict__ WtB, bf16* __restrict__ HtB,
    float* __restrict__ s2g, float* __restrict__ out) {
  // Xs[64][XS_PITCH] (phase B/C)  UNION  Hs[2][16384] (phase D)
  __shared__ __align__(16) char u_mem[64 * XS_PITCH * 2];      // 66,560 B
  __shared__ __align__(16) unsigned char gb_s[64][GROW];       // 17,408 B
  __shared__ float s2s[N_];                                    // 8,192 B
  __shared__ __align__(16) bf16 Ps[2][64][LDP];                // 10,240 B
  __shared__ float s1s[64];
  __shared__ float sum_part[64][8];
  __shared__ float row_sum[64];

  const int t = threadIdx.x;
  const int bid = blockIdx.x;
  const int b = bid & 7;            // XCD-affine: batch b -> XCD b
  const int i0 = (bid >> 3) * 64;   // this block's 64 rows within batch
  const int lane = t & 63, w = t >> 6;
  const int r31 = lane & 31, hf = lane >> 5;

  // ========== PHASE A: wa rows + WtB convert + graph pack ==========
  if (w < 2) {  // waves 0,1: one wa row each (k_wa pattern)
    const int row = bid * 2 + w;
    const float* wr = W + (size_t)row * D_;
    float d1 = 0.f, d2 = 0.f;
#pragma unroll
    for (int p = 0; p < 8; ++p) {
      int c = lane + p * 64;
      float wv = wr[c];
      d1 = fmaf(wv, a1[c], d1);
      d2 = fmaf(wv, a2[c], d2);
    }
#pragma unroll
    for (int off = 32; off > 0; off >>= 1) {
      d1 += __shfl_down(d1, off, 64);
      d2 += __shfl_down(d2, off, 64);
    }
    if (lane == 0) {
      wa1g[row] = d1;
      wa2g[row] = d2;
    }
  }
  if (t < 128) {  // 2 WtB chunks per block
    const int c = bid * 2 + (t >> 6);
    const int l = t & 63;
    const int db = c >> 5, kc = c & 31;
    const int dout = db * 32 + (l & 31);
    const int dbase = kc * 16 + (l >> 5) * 8;
    bf16 v[8];
#pragma unroll
    for (int e = 0; e < 8; ++e) v[e] = (bf16)W[(size_t)(dbase + e) * D_ + dout];
    *(bf16x8*)&WtB[((size_t)c * 64 + l) * 8] = *(bf16x8*)v;
  }
  {  // graph pack: own 64 rows -> gb_s bits (the compulsory 134MB HBM stream)
    const int gr = t >> 3;
    const int* grow = G + (size_t)(b * N_ + i0 + gr) * N_;
    unsigned int* gw = (unsigned int*)&gb_s[gr][0];
#pragma unroll 2
    for (int s = 0; s < 8; ++s) {
      const int widx = (t & 7) + s * 8;
      const int* src = grow + widx * 32;
      unsigned int bits = 0;
#pragma unroll
      for (int p = 0; p < 8; ++p) {
        int4 v = *(const int4*)&src[p * 4];
        bits |= (unsigned)(v.x != 0) << (p * 4);
        bits |= (unsigned)(v.y != 0) << (p * 4 + 1);
        bits |= (unsigned)(v.z != 0) << (p * 4 + 2);
        bits |= (unsigned)(v.w != 0) << (p * 4 + 3);
      }
      gw[widx] = bits;
    }
  }
  __threadfence();
  cg::this_grid().sync();  // wa + WtB globally visible

  // ========== PHASE B: s1/s2 for own rows + Xs (bf16) fill ==========
  bf16* Xs = (bf16*)u_mem;  // [64][XS_PITCH]
  {
    float wl1[8], wl2[8];
#pragma unroll
    for (int e = 0; e < 8; ++e) {
      wl1[e] = wa1g[lane * 8 + e];
      wl2[e] = wa2g[lane * 8 + e];
    }
#pragma unroll
    for (int q = 0; q < 8; ++q) {
      const int rr = w * 8 + q;
      const float* xr = X + (size_t)(b * N_ + i0 + rr) * D_;
      float4 xa = *(const float4*)&xr[lane * 8];
      float4 xb = *(const float4*)&xr[lane * 8 + 4];
      float xv[8] = {xa.x, xa.y, xa.z, xa.w, xb.x, xb.y, xb.z, xb.w};
      float d1 = 0.f, d2 = 0.f;
      bf16 hv[8];
#pragma unroll
      for (int e = 0; e < 8; ++e) {
        d1 = fmaf(xv[e], wl1[e], d1);
        d2 = fmaf(xv[e], wl2[e], d2);
        hv[e] = (bf16)xv[e];
      }
      *(bf16x8*)&Xs[rr * XS_PITCH + lane * 8] = *(bf16x8*)hv;
#pragma unroll
      for (int off = 32; off > 0; off >>= 1) {
        d1 += __shfl_down(d1, off, 64);
        d2 += __shfl_down(d2, off, 64);
      }
      if (lane == 0) {
        s1s[rr] = d1;
        s2g[b * N_ + i0 + rr] = d2;
      }
    }
  }
  __syncthreads();  // Xs ready (block-local)

  // ========== PHASE C: H-GEMM 64x512 (K=512), barrier-free K-loop ==========
  {
    f32x16 hacc[2][2];
#pragma unroll
    for (int i = 0; i < 2; ++i)
#pragma unroll
      for (int j = 0; j < 2; ++j)
#pragma unroll
        for (int r = 0; r < 16; ++r) hacc[i][j][r] = 0.f;

#pragma unroll 4
    for (int kc = 0; kc < 32; ++kc) {
      bf16x8 aF[2], bF[2];
#pragma unroll
      for (int rt = 0; rt < 2; ++rt)
        aF[rt] = *(const bf16x8*)&Xs[(rt * 32 + r31) * XS_PITCH + kc * 16 + hf * 8];
#pragma unroll
      for (int nt = 0; nt < 2; ++nt)
        bF[nt] = *(const bf16x8*)&WtB[(((size_t)(w * 2 + nt) * 32 + kc) * 64 + lane) * 8];
#pragma unroll
      for (int rt = 0; rt < 2; ++rt)
#pragma unroll
        for (int nt = 0; nt < 2; ++nt)
          hacc[rt][nt] = __builtin_amdgcn_mfma_f32_32x32x16_bf16(
              aF[rt], bF[nt], hacc[rt][nt], 0, 0, 0);
    }
    // write H (frag layout), rows i0..i0+63, all 512 dout
    bf16* Hb = HtB + (size_t)b * HTB_BATCH;
#pragma unroll
    for (int rt = 0; rt < 2; ++rt)
#pragma unroll
      for (int nt = 0; nt < 2; ++nt) {
        const int dout = (w * 2 + nt) * 32 + r31;
#pragma unroll
        for (int r = 0; r < 16; ++r) {
          const int J = i0 + rt * 32 + (r & 3) + 8 * (r >> 2) + 4 * hf;
          size_t addr = ((size_t)((dout >> 5) * (N_ / 16) + (J >> 4)) * 64 +
                         ((J >> 3) & 1) * 32 + (dout & 31)) *
                            8 +
                        (J & 7);
          Hb[addr] = (bf16)hacc[rt][nt][r];
        }
      }
  }
  __threadfence();
  cg::this_grid().sync();  // HtB + s2g globally visible

  // ========== PHASE D: attn (v7 pipeline, mask already in LDS) ==========
  bf16* HsF = (bf16*)u_mem;  // [2][16384] bf16 (reuses Xs region)
  const bf16* Hb = HtB + (size_t)b * HTB_BATCH;

  for (int c = t; c < N_; c += 512) s2s[c] = s2g[b * N_ + c];

  const int pi = t >> 3;
  const int c8 = t & 7;
  const int pj = c8 * 4;
  const float s1r = s1s[pi];
  float rsum = 0.f;

  f32x16 acc[2][2];
#pragma unroll
  for (int i = 0; i < 2; ++i)
#pragma unroll
    for (int j = 0; j < 2; ++j)
#pragma unroll
      for (int r = 0; r < 16; ++r) acc[i][j][r] = 0.f;

  // prologue: stage it=0 B-chunks into Hs[0] (wave-local, 4 gload_lds)
#pragma unroll
  for (int nt = 0; nt < 2; ++nt)
#pragma unroll
    for (int jo = 0; jo < 2; ++jo) {
      const bf16* src =
          &Hb[((size_t)(w * 2 + nt) * (N_ / 16) + jo) * 512 + lane * 8];
      __builtin_amdgcn_global_load_lds(
          (const __attribute__((address_space(1))) void*)src,
          (__attribute__((address_space(3))) void*)&HsF[w * 2048 +
                                                        (nt * 2 + jo) * 512],
          16, 0, 0);
    }
  __syncthreads();  // s2s ready + prologue stage drained (vmcnt 0)

#pragma unroll 1
  for (int it = 0; it < NIT; ++it) {
    const int cur = it & 1;
    {  // P-compute (4 values/thread)
      unsigned gbits =
          (unsigned)(gb_s[pi][it * 4 + (c8 >> 1)]) >> ((c8 & 1) * 4);
      f32x4 sv = *(const f32x4*)&s2s[it * AT_BK + pj];
      float pv[4];
#pragma unroll
      for (int q_ = 0; q_ < 4; ++q_) {
        float e = s1r + sv[q_];
        e = (e > 0.f) ? e : NEG_ALPHA * e;
        pv[q_] = ((gbits >> q_) & 1) ? __expf(e) : 0.f;
        rsum += pv[q_];
      }
      bf16x4 pb = {(bf16)pv[0], (bf16)pv[1], (bf16)pv[2], (bf16)pv[3]};
      *(bf16x4*)&Ps[cur][pi][pj] = pb;
    }
    {  // issue stage for it+1 into Hs[cur^1] (wave-local)
      const int jn = (it + 1 < NIT) ? it + 1 : 0;
#pragma unroll
      for (int nt = 0; nt < 2; ++nt)
#pragma unroll
        for (int jo = 0; jo < 2; ++jo) {
          const bf16* src = &Hb[((size_t)(w * 2 + nt) * (N_ / 16) + jn * 2 + jo) *
                                    512 +
                                lane * 8];
          __builtin_amdgcn_global_load_lds(
              (const __attribute__((address_space(1))) void*)src,
              (__attribute__((address_space(3))) void*)&HsF[(cur ^ 1) * 16384 +
                                                            w * 2048 +
                                                            (nt * 2 + jo) * 512],
              16, 0, 0);
        }
    }
    // barrier protocol: drain DS, sync, wait only PREVIOUS stage
    asm volatile("s_waitcnt lgkmcnt(0)" ::: "memory");
    __builtin_amdgcn_sched_barrier(0);
    __builtin_amdgcn_s_barrier();
    __builtin_amdgcn_sched_barrier(0);
    asm volatile("s_waitcnt vmcnt(4)" ::: "memory");
    __builtin_amdgcn_sched_barrier(0);
    // MFMA phase: A from Ps[cur], B from Hs[cur]
#pragma unroll
    for (int ks = 0; ks < 2; ++ks) {
      const int ko = ks * 16 + hf * 8;
      bf16x8 a0 = *(const bf16x8*)&Ps[cur][r31][ko];
      bf16x8 a1 = *(const bf16x8*)&Ps[cur][32 + r31][ko];
      bf16x8 b0 = *(const bf16x8*)&HsF[cur * 16384 + w * 2048 + ks * 512 + lane * 8];
      bf16x8 b1 =
          *(const bf16x8*)&HsF[cur * 16384 + w * 2048 + (2 + ks) * 512 + lane * 8];
      acc[0][0] = __builtin_amdgcn_mfma_f32_32x32x16_bf16(a0, b0, acc[0][0], 0, 0, 0);
      acc[0][1] = __builtin_amdgcn_mfma_f32_32x32x16_bf16(a0, b1, acc[0][1], 0, 0, 0);
      acc[1][0] = __builtin_amdgcn_mfma_f32_32x32x16_bf16(a1, b0, acc[1][0], 0, 0, 0);
      acc[1][1] = __builtin_amdgcn_mfma_f32_32x32x16_bf16(a1, b1, acc[1][1], 0, 0, 0);
    }
  }

  // row sums
  sum_part[pi][c8] = rsum;
  __syncthreads();
  if (t < 64) {
    float s = 0.f;
#pragma unroll
    for (int k = 0; k < 8; ++k) s += sum_part[t][k];
    row_sum[t] = s;
  }
  __syncthreads();

  // epilogue: normalize + elu + store
#pragma unroll
  for (int mt = 0; mt < 2; ++mt) {
    float inv[16];
#pragma unroll
    for (int r = 0; r < 16; ++r)
      inv[r] = 1.f / row_sum[mt * 32 + (r & 3) + 8 * (r >> 2) + 4 * hf];
#pragma unroll
    for (int nt = 0; nt < 2; ++nt) {
      const int d = w * 64 + nt * 32 + r31;
#pragma unroll
      for (int r = 0; r < 16; ++r) {
        int i = mt * 32 + (r & 3) + 8 * (r >> 2) + 4 * hf;
        float x = acc[mt][nt][r] * inv[r];
        out[((size_t)b * N_ + i0 + i) * D_ + d] =
            (x > 0.f) ? x : (__expf(x) - 1.f);
      }
    }
  }
}

// ---------------------------------------------------------------------------
extern "C" void kernel_launch(void* const* d_in, const int* in_sizes, int n_in,
                              void* d_out, int out_size, void* d_ws,
                              size_t ws_size, hipStream_t stream) {
  const float* X = (const float*)d_in[0];
  const int* G = (const int*)d_in[1];
  const float* W = (const float*)d_in[2];
  const float* a1 = (const float*)d_in[3];
  const float* a2 = (const float*)d_in[4];
  float* out = (float*)d_out;

  char* ws = (char*)d_ws;
  bf16* WtB = (bf16*)ws;                          // 0.5 MB (frag-tiled W)
  bf16* HtB = (bf16*)(ws + (1 << 20));            // 16 MB (frag-tiled H)
  float* wa1g = (float*)(ws + (1 << 20) + (16 << 20));
  float* wa2g = wa1g + D_;
  float* s2g = wa2g + D_;  // 64 KB

  void* args[] = {&X, &G, &W, &a1, &a2, &wa1g, &wa2g, &WtB, &HtB, &s2g, &out};
  hipLaunchCooperativeKernel((const void*)k_fused, dim3(256), dim3(512), args,
                             0, stream);
}

// Round 8
// 372.625 us; speedup vs baseline: 1.3727x; 1.3727x over previous
//
#include <hip/hip_runtime.h>
#include <math.h>

#define B_ 8
#define N_ 2048
#define D_ 512
#define NROWS (B_ * N_)  // 16384
#define NEG_ALPHA 0.1f

typedef __bf16 bf16;
typedef __bf16 bf16x4 __attribute__((ext_vector_type(4)));
typedef __bf16 bf16x8 __attribute__((ext_vector_type(8)));
typedef float f32x4 __attribute__((ext_vector_type(4)));
typedef float f32x16 __attribute__((ext_vector_type(16)));

// HtB layout: per batch b (2 MB): chunk c = (d>>5)*(N_/16) + (j>>4), each
// chunk = 64 lanes x 8 bf16 (1 KB); (l,e) <-> d = (c_d)*32 + (l&31),
// j = (c_j)*16 + (l>>5)*8 + e.  Exactly the mfma_32x32x16 B-fragment order.
#define HTB_BATCH ((D_ / 32) * (N_ / 16) * 512)  // 2 MB

// ---------------------------------------------------------------------------
// k_pre0: merged {W transpose -> Wt bf16} + {wa1/wa2 = W@a1 / W@a2}.
// Grid 192: blocks [0,64) prep 64x64 tiles; [64,192) wa rows (4/block).
// No intra-kernel dependency (prep writes Wt; wa writes wa1/wa2; nothing
// here reads either).
// ---------------------------------------------------------------------------
__global__ __launch_bounds__(256) void k_pre0(const float* __restrict__ W,
                                              bf16* __restrict__ Wt,
                                              const float* __restrict__ a1,
                                              const float* __restrict__ a2,
                                              float* __restrict__ wa1,
                                              float* __restrict__ wa2) {
  __shared__ float tile[64][65];
  const int bid = blockIdx.x;
  if (bid < 64) {  // ---- prep: Wt[dout][din] = bf16(W[din][dout]) ----
    const int din0 = (bid >> 3) * 64, dout0 = (bid & 7) * 64;
    const int tx = threadIdx.x & 63, tg = threadIdx.x >> 6;
#pragma unroll
    for (int rr = 0; rr < 16; ++rr) {
      int dr = tg * 16 + rr;
      tile[dr][tx] = W[(size_t)(din0 + dr) * D_ + dout0 + tx];
    }
    __syncthreads();
#pragma unroll
    for (int rr = 0; rr < 4; ++rr) {
      int dl = rr * 16 + (threadIdx.x >> 4);
      int nl = (threadIdx.x & 15) * 4;
      bf16x4 v = {(bf16)tile[nl][dl], (bf16)tile[nl + 1][dl],
                  (bf16)tile[nl + 2][dl], (bf16)tile[nl + 3][dl]};
      *(bf16x4*)&Wt[(size_t)(dout0 + dl) * D_ + din0 + nl] = v;
    }
  } else {  // ---- wa: 4 rows per block ----
    const int wv = threadIdx.x >> 6, lane = threadIdx.x & 63;
    const int row = (bid - 64) * 4 + wv;
    const float* wr = W + (size_t)row * D_;
    float d1 = 0.f, d2 = 0.f;
#pragma unroll
    for (int p = 0; p < 8; ++p) {
      int c = lane + p * 64;
      float w = wr[c];
      d1 = fmaf(w, a1[c], d1);
      d2 = fmaf(w, a2[c], d2);
    }
#pragma unroll
    for (int off = 32; off > 0; off >>= 1) {
      d1 += __shfl_down(d1, off, 64);
      d2 += __shfl_down(d2, off, 64);
    }
    if (lane == 0) {
      wa1[row] = d1;
      wa2[row] = d2;
    }
  }
}

// ---------------------------------------------------------------------------
// k_scores_x: s1/s2 = X.wa1 / X.wa2 (fp32) AND graph bit-pack (134MB stream).
// ---------------------------------------------------------------------------
__global__ __launch_bounds__(256) void k_scores_x(const float* __restrict__ X,
                                                  const float* __restrict__ wa1,
                                                  const float* __restrict__ wa2,
                                                  float* __restrict__ s1,
                                                  float* __restrict__ s2,
                                                  const int* __restrict__ G,
                                                  unsigned int* __restrict__ GB) {
  const int wv = threadIdx.x >> 6, lane = threadIdx.x & 63;
  const int r = blockIdx.x * 4 + wv;
  const float* x = X + (size_t)r * D_;
  float d1 = 0.f, d2 = 0.f;
#pragma unroll
  for (int p = 0; p < 2; ++p) {
    int c = lane * 4 + p * 256;
    float4 xv = *(const float4*)&x[c];
    float4 w1 = *(const float4*)&wa1[c];
    float4 w2 = *(const float4*)&wa2[c];
    d1 += xv.x * w1.x + xv.y * w1.y + xv.z * w1.z + xv.w * w1.w;
    d2 += xv.x * w2.x + xv.y * w2.y + xv.z * w2.z + xv.w * w2.w;
  }
  {
    const size_t g = (size_t)blockIdx.x * 256 + threadIdx.x;
    const int* src = G + g * 32;
    unsigned int bits = 0;
#pragma unroll
    for (int p = 0; p < 8; ++p) {
      int4 v = *(const int4*)&src[p * 4];
      bits |= (unsigned)(v.x != 0) << (p * 4);
      bits |= (unsigned)(v.y != 0) << (p * 4 + 1);
      bits |= (unsigned)(v.z != 0) << (p * 4 + 2);
      bits |= (unsigned)(v.w != 0) << (p * 4 + 3);
    }
    GB[g] = bits;
  }
#pragma unroll
  for (int off = 32; off > 0; off >>= 1) {
    d1 += __shfl_down(d1, off, 64);
    d2 += __shfl_down(d2, off, 64);
  }
  if (lane == 0) {
    s1[r] = d1;
    s2[r] = d2;
  }
}

// ---------------------------------------------------------------------------
// k_hiddenT (R2 version): HtB = bf16(X @ W) in frag layout.
// MEASUREMENT: launched with gridDim.z = 2 (identical duplicate pass) so the
// dispatch exceeds the ~80us fill threshold and shows in rocprof top-5.
// True single-pass cost = shown dur / 2.
// ---------------------------------------------------------------------------
#define LDH 40

__global__ __launch_bounds__(256, 2) void k_hiddenT(const float* __restrict__ X,
                                                    const bf16* __restrict__ Wt,
                                                    bf16* __restrict__ HtB) {
  __shared__ bf16 As[128][LDH];
  __shared__ bf16 Bs[128][LDH];
  const int t = threadIdx.x;
  const int m0 = blockIdx.y * 128;
  const int n0 = blockIdx.x * 128;
  const int lane = t & 63, w = t >> 6;
  const int wm = w >> 1, wn = w & 1;
  const int l15 = lane & 15, q = lane >> 4;

  f32x4 acc[4][4];
#pragma unroll
  for (int i = 0; i < 4; ++i)
#pragma unroll
    for (int j = 0; j < 4; ++j) acc[i][j] = (f32x4){0.f, 0.f, 0.f, 0.f};

  bf16x8 av[2];
  float4 bv[4];
#pragma unroll
  for (int p = 0; p < 2; ++p) {
    int s = t + p * 256;
    av[p] = *(const bf16x8*)&Wt[(size_t)(m0 + (s >> 2)) * D_ + (s & 3) * 8];
  }
#pragma unroll
  for (int p = 0; p < 4; ++p) {
    int s = t + p * 256;
    bv[p] = *(const float4*)&X[(size_t)(n0 + (s >> 3)) * D_ + (s & 7) * 4];
  }

  for (int k0 = 0; k0 < D_; k0 += 32) {
    __syncthreads();
#pragma unroll
    for (int p = 0; p < 2; ++p) {
      int s = t + p * 256;
      *(bf16x8*)&As[s >> 2][(s & 3) * 8] = av[p];
    }
#pragma unroll
    for (int p = 0; p < 4; ++p) {
      int s = t + p * 256;
      float4 v = bv[p];
      bf16x4 h = {(bf16)v.x, (bf16)v.y, (bf16)v.z, (bf16)v.w};
      *(bf16x4*)&Bs[s >> 3][(s & 7) * 4] = h;
    }
    __syncthreads();
    if (k0 + 32 < D_) {
#pragma unroll
      for (int p = 0; p < 2; ++p) {
        int s = t + p * 256;
        av[p] = *(const bf16x8*)&Wt[(size_t)(m0 + (s >> 2)) * D_ + k0 + 32 + (s & 3) * 8];
      }
#pragma unroll
      for (int p = 0; p < 4; ++p) {
        int s = t + p * 256;
        bv[p] = *(const float4*)&X[(size_t)(n0 + (s >> 3)) * D_ + k0 + 32 + (s & 7) * 4];
      }
    }
    bf16x8 a[4], bb[4];
#pragma unroll
    for (int i = 0; i < 4; ++i)
      a[i] = *(const bf16x8*)&As[wm * 64 + i * 16 + l15][q * 8];
#pragma unroll
    for (int j = 0; j < 4; ++j)
      bb[j] = *(const bf16x8*)&Bs[wn * 64 + j * 16 + l15][q * 8];
#pragma unroll
    for (int i = 0; i < 4; ++i)
#pragma unroll
      for (int j = 0; j < 4; ++j)
        acc[i][j] =
            __builtin_amdgcn_mfma_f32_16x16x32_bf16(a[i], bb[j], acc[i][j], 0, 0, 0);
  }
#pragma unroll
  for (int i = 0; i < 4; ++i)
#pragma unroll
    for (int r = 0; r < 4; ++r) {
      int dout = m0 + wm * 64 + i * 16 + q * 4 + r;
#pragma unroll
      for (int j = 0; j < 4; ++j) {
        int row = n0 + wn * 64 + j * 16 + l15;
        int bb_ = row >> 11;
        int jj = row & (N_ - 1);
        size_t addr = (size_t)bb_ * HTB_BATCH +
                      ((size_t)((dout >> 5) * (N_ / 16) + (jj >> 4)) * 64 +
                       ((jj >> 3) & 1) * 32 + (dout & 31)) *
                          8 +
                      (jj & 7);
        HtB[addr] = (bf16)acc[i][j][r];
      }
    }
}

// ---------------------------------------------------------------------------
// k_attn v7 (R6): counted-vmcnt async pipeline, mask bits in LDS.
// MEASUREMENT: gridDim.z = 2 duplicate pass (see k_hiddenT note).
// ---------------------------------------------------------------------------
#define AT_BM 64
#define AT_BK 32
#define LDP 40
#define NIT (N_ / AT_BK)  // 64
#define GROW 272

__global__ __launch_bounds__(512) void k_attn(const bf16* __restrict__ HtB,
                                              const unsigned char* __restrict__ GB,
                                              const float* __restrict__ s1,
                                              const float* __restrict__ s2,
                                              float* __restrict__ out) {
  __shared__ __align__(16) bf16 Ps[2][AT_BM][LDP];           // 10,240 B
  __shared__ __align__(16) bf16 Hs[2][16384];                // 65,536 B
  __shared__ float s2s[N_];                                  // 8 KB
  __shared__ __align__(16) unsigned char gb_s[AT_BM][GROW];  // 17,408 B
  __shared__ float sum_part[AT_BM][8];                       // 2 KB
  __shared__ float row_sum[AT_BM];

  const int t = threadIdx.x;
  const int bid = blockIdx.x;
  const int b = bid & 7;
  const int i0 = (bid >> 3) * AT_BM;
  const int lane = t & 63, w = t >> 6;
  const int r31 = lane & 31, hf = lane >> 5;

  const bf16* Hb = HtB + (size_t)b * HTB_BATCH;
  const unsigned char* GBb = GB + ((size_t)b * N_ + i0) * (N_ / 8);

  for (int c = t; c < N_; c += 512) s2s[c] = s2[b * N_ + c];
  {
    int gr = t >> 3, gc = (t & 7) * 32;
    int4 w0 = *(const int4*)&GBb[(size_t)gr * (N_ / 8) + gc];
    int4 w1 = *(const int4*)&GBb[(size_t)gr * (N_ / 8) + gc + 16];
    *(int4*)&gb_s[gr][gc] = w0;
    *(int4*)&gb_s[gr][gc + 16] = w1;
  }

  const int pi = t >> 3;
  const int c8 = t & 7;
  const int pj = c8 * 4;
  const float s1r = s1[b * N_ + i0 + pi];
  float rsum = 0.f;

  f32x16 acc[2][2];
#pragma unroll
  for (int i = 0; i < 2; ++i)
#pragma unroll
    for (int j = 0; j < 2; ++j)
#pragma unroll
      for (int r = 0; r < 16; ++r) acc[i][j][r] = 0.f;

  bf16* HsF = &Hs[0][0];
#pragma unroll
  for (int nt = 0; nt < 2; ++nt)
#pragma unroll
    for (int jo = 0; jo < 2; ++jo) {
      const bf16* src =
          &Hb[((size_t)(w * 2 + nt) * (N_ / 16) + jo) * 512 + lane * 8];
      __builtin_amdgcn_global_load_lds(
          (const __attribute__((address_space(1))) void*)src,
          (__attribute__((address_space(3))) void*)
              &HsF[w * 2048 + (nt * 2 + jo) * 512],
          16, 0, 0);
    }

  __syncthreads();  // s2s + gb_s ready (also drains prologue stage)

#pragma unroll 1
  for (int it = 0; it < NIT; ++it) {
    const int cur = it & 1;
    {
      unsigned gbits = (unsigned)(gb_s[pi][it * 4 + (c8 >> 1)]) >> ((c8 & 1) * 4);
      f32x4 sv = *(const f32x4*)&s2s[it * AT_BK + pj];
      float pv[4];
#pragma unroll
      for (int q_ = 0; q_ < 4; ++q_) {
        float e = s1r + sv[q_];
        e = (e > 0.f) ? e : NEG_ALPHA * e;
        pv[q_] = ((gbits >> q_) & 1) ? __expf(e) : 0.f;
        rsum += pv[q_];
      }
      bf16x4 pb = {(bf16)pv[0], (bf16)pv[1], (bf16)pv[2], (bf16)pv[3]};
      *(bf16x4*)&Ps[cur][pi][pj] = pb;
    }
    {
      const int jn = (it + 1 < NIT) ? it + 1 : 0;
#pragma unroll
      for (int nt = 0; nt < 2; ++nt)
#pragma unroll
        for (int jo = 0; jo < 2; ++jo) {
          const bf16* src = &Hb[((size_t)(w * 2 + nt) * (N_ / 16) + jn * 2 + jo) *
                                    512 +
                                lane * 8];
          __builtin_amdgcn_global_load_lds(
              (const __attribute__((address_space(1))) void*)src,
              (__attribute__((address_space(3))) void*)
                  &HsF[(cur ^ 1) * 16384 + w * 2048 + (nt * 2 + jo) * 512],
              16, 0, 0);
        }
    }
    asm volatile("s_waitcnt lgkmcnt(0)" ::: "memory");
    __builtin_amdgcn_sched_barrier(0);
    __builtin_amdgcn_s_barrier();
    __builtin_amdgcn_sched_barrier(0);
    asm volatile("s_waitcnt vmcnt(4)" ::: "memory");
    __builtin_amdgcn_sched_barrier(0);
#pragma unroll
    for (int ks = 0; ks < 2; ++ks) {
      const int ko = ks * 16 + hf * 8;
      bf16x8 a0 = *(const bf16x8*)&Ps[cur][r31][ko];
      bf16x8 a1 = *(const bf16x8*)&Ps[cur][32 + r31][ko];
      bf16x8 b0 = *(const bf16x8*)&HsF[cur * 16384 + w * 2048 + ks * 512 + lane * 8];
      bf16x8 b1 =
          *(const bf16x8*)&HsF[cur * 16384 + w * 2048 + (2 + ks) * 512 + lane * 8];
      acc[0][0] = __builtin_amdgcn_mfma_f32_32x32x16_bf16(a0, b0, acc[0][0], 0, 0, 0);
      acc[0][1] = __builtin_amdgcn_mfma_f32_32x32x16_bf16(a0, b1, acc[0][1], 0, 0, 0);
      acc[1][0] = __builtin_amdgcn_mfma_f32_32x32x16_bf16(a1, b0, acc[1][0], 0, 0, 0);
      acc[1][1] = __builtin_amdgcn_mfma_f32_32x32x16_bf16(a1, b1, acc[1][1], 0, 0, 0);
    }
  }

  sum_part[pi][c8] = rsum;
  __syncthreads();
  if (t < AT_BM) {
    float s = 0.f;
#pragma unroll
    for (int k = 0; k < 8; ++k) s += sum_part[t][k];
    row_sum[t] = s;
  }
  __syncthreads();

#pragma unroll
  for (int mt = 0; mt < 2; ++mt) {
    float inv[16];
#pragma unroll
    for (int r = 0; r < 16; ++r)
      inv[r] = 1.f / row_sum[mt * 32 + (r & 3) + 8 * (r >> 2) + 4 * hf];
#pragma unroll
    for (int nt = 0; nt < 2; ++nt) {
      const int d = w * 64 + nt * 32 + r31;
#pragma unroll
      for (int r = 0; r < 16; ++r) {
        int i = mt * 32 + (r & 3) + 8 * (r >> 2) + 4 * hf;
        float x = acc[mt][nt][r] * inv[r];
        out[((size_t)b * N_ + i0 + i) * D_ + d] =
            (x > 0.f) ? x : (__expf(x) - 1.f);
      }
    }
  }
}

// ---------------------------------------------------------------------------
extern "C" void kernel_launch(void* const* d_in, const int* in_sizes, int n_in,
                              void* d_out, int out_size, void* d_ws,
                              size_t ws_size, hipStream_t stream) {
  const float* X = (const float*)d_in[0];
  const int* graph = (const int*)d_in[1];
  const float* W = (const float*)d_in[2];
  const float* a1 = (const float*)d_in[3];
  const float* a2 = (const float*)d_in[4];
  float* out = (float*)d_out;

  char* ws = (char*)d_ws;
  bf16* Wt = (bf16*)ws;                                              // 0.5 MB
  bf16* HtB = (bf16*)(ws + (1 << 19));                               // 16 MB
  unsigned int* GBw = (unsigned int*)(ws + (1 << 19) + (16 << 20));  // 4 MB
  float* s1 = (float*)(ws + (1 << 19) + (21 << 20));
  float* s2 = s1 + NROWS;
  float* wa1 = s2 + NROWS;
  float* wa2 = wa1 + D_;

  hipLaunchKernelGGL(k_pre0, dim3(192), dim3(256), 0, stream, W, Wt, a1, a2,
                     wa1, wa2);
  hipLaunchKernelGGL(k_scores_x, dim3(NROWS / 4), dim3(256), 0, stream, X, wa1,
                     wa2, s1, s2, graph, GBw);
  // z=2: duplicate pass for rocprof visibility (true cost = dur/2)
  hipLaunchKernelGGL(k_hiddenT, dim3(NROWS / 128, D_ / 128, 2), dim3(256), 0,
                     stream, X, Wt, HtB);
  hipLaunchKernelGGL(k_attn, dim3(N_ / AT_BM * B_, 1, 2), dim3(512), 0, stream,
                     HtB, (const unsigned char*)GBw, s1, s2, out);
}

// Round 9
// 302.955 us; speedup vs baseline: 1.6884x; 1.2300x over previous
//
#include <hip/hip_runtime.h>
#include <math.h>

#define B_ 8
#define N_ 2048
#define D_ 512
#define NROWS (B_ * N_)  // 16384
#define NEG_ALPHA 0.1f

typedef __bf16 bf16;
typedef __bf16 bf16x4 __attribute__((ext_vector_type(4)));
typedef __bf16 bf16x8 __attribute__((ext_vector_type(8)));
typedef float f32x4 __attribute__((ext_vector_type(4)));
typedef float f32x16 __attribute__((ext_vector_type(16)));

// HtB layout: per batch b (2 MB): chunk c = (d>>5)*(N_/16) + (j>>4), each
// chunk = 64 lanes x 8 bf16 (1 KB); (l,e) <-> d = (c_d)*32 + (l&31),
// j = (c_j)*16 + (l>>5)*8 + e.  Exactly the mfma_32x32x16 B-fragment order.
#define HTB_BATCH ((D_ / 32) * (N_ / 16) * 512)  // 2 MB

// ---------------------------------------------------------------------------
// k_pre0: merged {W transpose -> Wt bf16} + {wa1/wa2 = W@a1 / W@a2}.
// ---------------------------------------------------------------------------
__global__ __launch_bounds__(256) void k_pre0(const float* __restrict__ W,
                                              bf16* __restrict__ Wt,
                                              const float* __restrict__ a1,
                                              const float* __restrict__ a2,
                                              float* __restrict__ wa1,
                                              float* __restrict__ wa2) {
  __shared__ float tile[64][65];
  const int bid = blockIdx.x;
  if (bid < 64) {  // ---- prep: Wt[dout][din] = bf16(W[din][dout]) ----
    const int din0 = (bid >> 3) * 64, dout0 = (bid & 7) * 64;
    const int tx = threadIdx.x & 63, tg = threadIdx.x >> 6;
#pragma unroll
    for (int rr = 0; rr < 16; ++rr) {
      int dr = tg * 16 + rr;
      tile[dr][tx] = W[(size_t)(din0 + dr) * D_ + dout0 + tx];
    }
    __syncthreads();
#pragma unroll
    for (int rr = 0; rr < 4; ++rr) {
      int dl = rr * 16 + (threadIdx.x >> 4);
      int nl = (threadIdx.x & 15) * 4;
      bf16x4 v = {(bf16)tile[nl][dl], (bf16)tile[nl + 1][dl],
                  (bf16)tile[nl + 2][dl], (bf16)tile[nl + 3][dl]};
      *(bf16x4*)&Wt[(size_t)(dout0 + dl) * D_ + din0 + nl] = v;
    }
  } else {  // ---- wa: 4 rows per block ----
    const int wv = threadIdx.x >> 6, lane = threadIdx.x & 63;
    const int row = (bid - 64) * 4 + wv;
    const float* wr = W + (size_t)row * D_;
    float d1 = 0.f, d2 = 0.f;
#pragma unroll
    for (int p = 0; p < 8; ++p) {
      int c = lane + p * 64;
      float w = wr[c];
      d1 = fmaf(w, a1[c], d1);
      d2 = fmaf(w, a2[c], d2);
    }
#pragma unroll
    for (int off = 32; off > 0; off >>= 1) {
      d1 += __shfl_down(d1, off, 64);
      d2 += __shfl_down(d2, off, 64);
    }
    if (lane == 0) {
      wa1[row] = d1;
      wa2[row] = d2;
    }
  }
}

// ---------------------------------------------------------------------------
// k_scores_x: s1/s2 = X.wa1 / X.wa2 (fp32) AND graph bit-pack (134MB stream).
// ---------------------------------------------------------------------------
__global__ __launch_bounds__(256) void k_scores_x(const float* __restrict__ X,
                                                  const float* __restrict__ wa1,
                                                  const float* __restrict__ wa2,
                                                  float* __restrict__ s1,
                                                  float* __restrict__ s2,
                                                  const int* __restrict__ G,
                                                  unsigned int* __restrict__ GB) {
  const int wv = threadIdx.x >> 6, lane = threadIdx.x & 63;
  const int r = blockIdx.x * 4 + wv;
  const float* x = X + (size_t)r * D_;
  float d1 = 0.f, d2 = 0.f;
#pragma unroll
  for (int p = 0; p < 2; ++p) {
    int c = lane * 4 + p * 256;
    float4 xv = *(const float4*)&x[c];
    float4 w1 = *(const float4*)&wa1[c];
    float4 w2 = *(const float4*)&wa2[c];
    d1 += xv.x * w1.x + xv.y * w1.y + xv.z * w1.z + xv.w * w1.w;
    d2 += xv.x * w2.x + xv.y * w2.y + xv.z * w2.z + xv.w * w2.w;
  }
  {
    const size_t g = (size_t)blockIdx.x * 256 + threadIdx.x;
    const int* src = G + g * 32;
    unsigned int bits = 0;
#pragma unroll
    for (int p = 0; p < 8; ++p) {
      int4 v = *(const int4*)&src[p * 4];
      bits |= (unsigned)(v.x != 0) << (p * 4);
      bits |= (unsigned)(v.y != 0) << (p * 4 + 1);
      bits |= (unsigned)(v.z != 0) << (p * 4 + 2);
      bits |= (unsigned)(v.w != 0) << (p * 4 + 3);
    }
    GB[g] = bits;
  }
#pragma unroll
  for (int off = 32; off > 0; off >>= 1) {
    d1 += __shfl_down(d1, off, 64);
    d2 += __shfl_down(d2, off, 64);
  }
  if (lane == 0) {
    s1[r] = d1;
    s2[r] = d2;
  }
}

// ---------------------------------------------------------------------------
// k_hiddenT (R2 version): HtB = bf16(X @ W) in frag layout.
// ---------------------------------------------------------------------------
#define LDH 40

__global__ __launch_bounds__(256, 2) void k_hiddenT(const float* __restrict__ X,
                                                    const bf16* __restrict__ Wt,
                                                    bf16* __restrict__ HtB) {
  __shared__ bf16 As[128][LDH];
  __shared__ bf16 Bs[128][LDH];
  const int t = threadIdx.x;
  const int m0 = blockIdx.y * 128;
  const int n0 = blockIdx.x * 128;
  const int lane = t & 63, w = t >> 6;
  const int wm = w >> 1, wn = w & 1;
  const int l15 = lane & 15, q = lane >> 4;

  f32x4 acc[4][4];
#pragma unroll
  for (int i = 0; i < 4; ++i)
#pragma unroll
    for (int j = 0; j < 4; ++j) acc[i][j] = (f32x4){0.f, 0.f, 0.f, 0.f};

  bf16x8 av[2];
  float4 bv[4];
#pragma unroll
  for (int p = 0; p < 2; ++p) {
    int s = t + p * 256;
    av[p] = *(const bf16x8*)&Wt[(size_t)(m0 + (s >> 2)) * D_ + (s & 3) * 8];
  }
#pragma unroll
  for (int p = 0; p < 4; ++p) {
    int s = t + p * 256;
    bv[p] = *(const float4*)&X[(size_t)(n0 + (s >> 3)) * D_ + (s & 7) * 4];
  }

  for (int k0 = 0; k0 < D_; k0 += 32) {
    __syncthreads();
#pragma unroll
    for (int p = 0; p < 2; ++p) {
      int s = t + p * 256;
      *(bf16x8*)&As[s >> 2][(s & 3) * 8] = av[p];
    }
#pragma unroll
    for (int p = 0; p < 4; ++p) {
      int s = t + p * 256;
      float4 v = bv[p];
      bf16x4 h = {(bf16)v.x, (bf16)v.y, (bf16)v.z, (bf16)v.w};
      *(bf16x4*)&Bs[s >> 3][(s & 7) * 4] = h;
    }
    __syncthreads();
    if (k0 + 32 < D_) {
#pragma unroll
      for (int p = 0; p < 2; ++p) {
        int s = t + p * 256;
        av[p] = *(const bf16x8*)&Wt[(size_t)(m0 + (s >> 2)) * D_ + k0 + 32 + (s & 3) * 8];
      }
#pragma unroll
      for (int p = 0; p < 4; ++p) {
        int s = t + p * 256;
        bv[p] = *(const float4*)&X[(size_t)(n0 + (s >> 3)) * D_ + k0 + 32 + (s & 7) * 4];
      }
    }
    bf16x8 a[4], bb[4];
#pragma unroll
    for (int i = 0; i < 4; ++i)
      a[i] = *(const bf16x8*)&As[wm * 64 + i * 16 + l15][q * 8];
#pragma unroll
    for (int j = 0; j < 4; ++j)
      bb[j] = *(const bf16x8*)&Bs[wn * 64 + j * 16 + l15][q * 8];
#pragma unroll
    for (int i = 0; i < 4; ++i)
#pragma unroll
      for (int j = 0; j < 4; ++j)
        acc[i][j] =
            __builtin_amdgcn_mfma_f32_16x16x32_bf16(a[i], bb[j], acc[i][j], 0, 0, 0);
  }
#pragma unroll
  for (int i = 0; i < 4; ++i)
#pragma unroll
    for (int r = 0; r < 4; ++r) {
      int dout = m0 + wm * 64 + i * 16 + q * 4 + r;
#pragma unroll
      for (int j = 0; j < 4; ++j) {
        int row = n0 + wn * 64 + j * 16 + l15;
        int bb_ = row >> 11;
        int jj = row & (N_ - 1);
        size_t addr = (size_t)bb_ * HTB_BATCH +
                      ((size_t)((dout >> 5) * (N_ / 16) + (jj >> 4)) * 64 +
                       ((jj >> 3) & 1) * 32 + (dout & 31)) *
                          8 +
                      (jj & 7);
        HtB[addr] = (bf16)acc[i][j][r];
      }
    }
}

// ---------------------------------------------------------------------------
// k_attn v8: d-SPLIT of the v7 counted-vmcnt pipeline.
// Each block: 64 rows x 256 d (ds = bid>>8), grid 512 -> 2 blocks/CU
// (~70 KB LDS). L2 B-traffic unchanged (each block stages only its d-half:
// 2 gload_lds/iter/wave, vmcnt(2)). P-compute duplicated across the pair --
// it runs inside the partner block's barrier stalls. Mask bits in LDS.
// ---------------------------------------------------------------------------
#define AT_BM 64
#define AT_BK 32
#define LDP 40
#define NIT (N_ / AT_BK)  // 64
#define GROW 272

__global__ __launch_bounds__(512, 4) void k_attn(const bf16* __restrict__ HtB,
                                                 const unsigned char* __restrict__ GB,
                                                 const float* __restrict__ s1,
                                                 const float* __restrict__ s2,
                                                 float* __restrict__ out) {
  __shared__ __align__(16) bf16 Ps[2][AT_BM][LDP];           // 10,240 B
  __shared__ __align__(16) bf16 Hs[2][8192];                 // 32,768 B
  __shared__ float s2s[N_];                                  // 8 KB
  __shared__ __align__(16) unsigned char gb_s[AT_BM][GROW];  // 17,408 B
  __shared__ float sum_part[AT_BM][8];                       // 2 KB
  __shared__ float row_sum[AT_BM];

  const int t = threadIdx.x;
  const int bid = blockIdx.x;
  const int b = bid & 7;                    // XCD-affine: batch b -> XCD b
  const int i0 = ((bid >> 3) & 31) * AT_BM; // row tile
  const int ds = bid >> 8;                  // d-half: 0 or 1
  const int lane = t & 63, w = t >> 6;
  const int r31 = lane & 31, hf = lane >> 5;
  const int dch = ds * 8 + w;               // this wave's 32-d chunk index

  const bf16* Hb = HtB + (size_t)b * HTB_BATCH;
  const unsigned char* GBb = GB + ((size_t)b * N_ + i0) * (N_ / 8);

  for (int c = t; c < N_; c += 512) s2s[c] = s2[b * N_ + c];
  {  // graph bits for this block's 64 rows: 16 KB, loaded once
    int gr = t >> 3, gc = (t & 7) * 32;
    int4 w0 = *(const int4*)&GBb[(size_t)gr * (N_ / 8) + gc];
    int4 w1 = *(const int4*)&GBb[(size_t)gr * (N_ / 8) + gc + 16];
    *(int4*)&gb_s[gr][gc] = w0;
    *(int4*)&gb_s[gr][gc + 16] = w1;
  }

  const int pi = t >> 3;
  const int c8 = t & 7;
  const int pj = c8 * 4;
  const float s1r = s1[b * N_ + i0 + pi];
  float rsum = 0.f;

  f32x16 acc[2];
#pragma unroll
  for (int i = 0; i < 2; ++i)
#pragma unroll
    for (int r = 0; r < 16; ++r) acc[i][r] = 0.f;

  // prologue: stage it=0 (wave-local: 2 chunks of this wave's d-chunk)
  bf16* HsF = &Hs[0][0];
#pragma unroll
  for (int jo = 0; jo < 2; ++jo) {
    const bf16* src = &Hb[((size_t)dch * (N_ / 16) + jo) * 512 + lane * 8];
    __builtin_amdgcn_global_load_lds(
        (const __attribute__((address_space(1))) void*)src,
        (__attribute__((address_space(3))) void*)&HsF[w * 1024 + jo * 512], 16,
        0, 0);
  }

  __syncthreads();  // s2s + gb_s ready (also drains prologue stage)

#pragma unroll 1
  for (int it = 0; it < NIT; ++it) {
    const int cur = it & 1;
    {  // P-compute (4 values/thread)
      unsigned gbits = (unsigned)(gb_s[pi][it * 4 + (c8 >> 1)]) >> ((c8 & 1) * 4);
      f32x4 sv = *(const f32x4*)&s2s[it * AT_BK + pj];
      float pv[4];
#pragma unroll
      for (int q_ = 0; q_ < 4; ++q_) {
        float e = s1r + sv[q_];
        e = (e > 0.f) ? e : NEG_ALPHA * e;
        pv[q_] = ((gbits >> q_) & 1) ? __expf(e) : 0.f;
        rsum += pv[q_];
      }
      bf16x4 pb = {(bf16)pv[0], (bf16)pv[1], (bf16)pv[2], (bf16)pv[3]};
      *(bf16x4*)&Ps[cur][pi][pj] = pb;
    }
    {  // issue stage for it+1 (wave-local, 2 loads)
      const int jn = (it + 1 < NIT) ? it + 1 : 0;
#pragma unroll
      for (int jo = 0; jo < 2; ++jo) {
        const bf16* src =
            &Hb[((size_t)dch * (N_ / 16) + jn * 2 + jo) * 512 + lane * 8];
        __builtin_amdgcn_global_load_lds(
            (const __attribute__((address_space(1))) void*)src,
            (__attribute__((address_space(3))) void*)
                &HsF[(cur ^ 1) * 8192 + w * 1024 + jo * 512],
            16, 0, 0);
      }
    }
    // barrier protocol: drain DS, sync, wait only PREVIOUS stage
    asm volatile("s_waitcnt lgkmcnt(0)" ::: "memory");
    __builtin_amdgcn_sched_barrier(0);
    __builtin_amdgcn_s_barrier();
    __builtin_amdgcn_sched_barrier(0);
    asm volatile("s_waitcnt vmcnt(2)" ::: "memory");
    __builtin_amdgcn_sched_barrier(0);
    // MFMA phase: A from Ps[cur], B from Hs[cur] (chunk jo == ks)
#pragma unroll
    for (int ks = 0; ks < 2; ++ks) {
      const int ko = ks * 16 + hf * 8;
      bf16x8 a0 = *(const bf16x8*)&Ps[cur][r31][ko];
      bf16x8 a1 = *(const bf16x8*)&Ps[cur][32 + r31][ko];
      bf16x8 bB = *(const bf16x8*)&HsF[cur * 8192 + w * 1024 + ks * 512 + lane * 8];
      acc[0] = __builtin_amdgcn_mfma_f32_32x32x16_bf16(a0, bB, acc[0], 0, 0, 0);
      acc[1] = __builtin_amdgcn_mfma_f32_32x32x16_bf16(a1, bB, acc[1], 0, 0, 0);
    }
  }

  sum_part[pi][c8] = rsum;
  __syncthreads();
  if (t < AT_BM) {
    float s = 0.f;
#pragma unroll
    for (int k = 0; k < 8; ++k) s += sum_part[t][k];
    row_sum[t] = s;
  }
  __syncthreads();

  // epilogue: normalize + elu + store (this block's d-half only)
  // C/D layout (32x32): col = lane&31, row = (r&3) + 8*(r>>2) + 4*hf
#pragma unroll
  for (int mt = 0; mt < 2; ++mt) {
    float inv[16];
#pragma unroll
    for (int r = 0; r < 16; ++r)
      inv[r] = 1.f / row_sum[mt * 32 + (r & 3) + 8 * (r >> 2) + 4 * hf];
    const int d = ds * 256 + w * 32 + r31;
#pragma unroll
    for (int r = 0; r < 16; ++r) {
      int i = mt * 32 + (r & 3) + 8 * (r >> 2) + 4 * hf;
      float x = acc[mt][r] * inv[r];
      out[((size_t)b * N_ + i0 + i) * D_ + d] = (x > 0.f) ? x : (__expf(x) - 1.f);
    }
  }
}

// ---------------------------------------------------------------------------
extern "C" void kernel_launch(void* const* d_in, const int* in_sizes, int n_in,
                              void* d_out, int out_size, void* d_ws,
                              size_t ws_size, hipStream_t stream) {
  const float* X = (const float*)d_in[0];
  const int* graph = (const int*)d_in[1];
  const float* W = (const float*)d_in[2];
  const float* a1 = (const float*)d_in[3];
  const float* a2 = (const float*)d_in[4];
  float* out = (float*)d_out;

  char* ws = (char*)d_ws;
  bf16* Wt = (bf16*)ws;                                              // 0.5 MB
  bf16* HtB = (bf16*)(ws + (1 << 19));                               // 16 MB
  unsigned int* GBw = (unsigned int*)(ws + (1 << 19) + (16 << 20));  // 4 MB
  float* s1 = (float*)(ws + (1 << 19) + (21 << 20));
  float* s2 = s1 + NROWS;
  float* wa1 = s2 + NROWS;
  float* wa2 = wa1 + D_;

  hipLaunchKernelGGL(k_pre0, dim3(192), dim3(256), 0, stream, W, Wt, a1, a2,
                     wa1, wa2);
  hipLaunchKernelGGL(k_scores_x, dim3(NROWS / 4), dim3(256), 0, stream, X, wa1,
                     wa2, s1, s2, graph, GBw);
  hipLaunchKernelGGL(k_hiddenT, dim3(NROWS / 128, D_ / 128), dim3(256), 0,
                     stream, X, Wt, HtB);
  hipLaunchKernelGGL(k_attn, dim3(N_ / AT_BM * B_ * 2), dim3(512), 0, stream,
                     HtB, (const unsigned char*)GBw, s1, s2, out);
}

// Round 10
// 277.325 us; speedup vs baseline: 1.8444x; 1.0924x over previous
//
#include <hip/hip_runtime.h>
#include <math.h>

#define B_ 8
#define N_ 2048
#define D_ 512
#define NROWS (B_ * N_)  // 16384
#define NEG_ALPHA 0.1f

typedef __bf16 bf16;
typedef __bf16 bf16x4 __attribute__((ext_vector_type(4)));
typedef __bf16 bf16x8 __attribute__((ext_vector_type(8)));
typedef float f32x4 __attribute__((ext_vector_type(4)));
typedef float f32x16 __attribute__((ext_vector_type(16)));

// HtB layout: per batch b (2 MB): chunk c = (d>>5)*(N_/16) + (j>>4), each
// chunk = 64 lanes x 8 bf16 (1 KB); (l,e) <-> d = (c_d)*32 + (l&31),
// j = (c_j)*16 + (l>>5)*8 + e.  Exactly the mfma_32x32x16 B-fragment order.
#define HTB_BATCH ((D_ / 32) * (N_ / 16) * 512)  // 2 MB

// ---------------------------------------------------------------------------
// k_pre0: merged {W transpose -> Wt bf16} + {wa1/wa2 = W@a1 / W@a2}.
// ---------------------------------------------------------------------------
__global__ __launch_bounds__(256) void k_pre0(const float* __restrict__ W,
                                              bf16* __restrict__ Wt,
                                              const float* __restrict__ a1,
                                              const float* __restrict__ a2,
                                              float* __restrict__ wa1,
                                              float* __restrict__ wa2) {
  __shared__ float tile[64][65];
  const int bid = blockIdx.x;
  if (bid < 64) {  // ---- prep: Wt[dout][din] = bf16(W[din][dout]) ----
    const int din0 = (bid >> 3) * 64, dout0 = (bid & 7) * 64;
    const int tx = threadIdx.x & 63, tg = threadIdx.x >> 6;
#pragma unroll
    for (int rr = 0; rr < 16; ++rr) {
      int dr = tg * 16 + rr;
      tile[dr][tx] = W[(size_t)(din0 + dr) * D_ + dout0 + tx];
    }
    __syncthreads();
#pragma unroll
    for (int rr = 0; rr < 4; ++rr) {
      int dl = rr * 16 + (threadIdx.x >> 4);
      int nl = (threadIdx.x & 15) * 4;
      bf16x4 v = {(bf16)tile[nl][dl], (bf16)tile[nl + 1][dl],
                  (bf16)tile[nl + 2][dl], (bf16)tile[nl + 3][dl]};
      *(bf16x4*)&Wt[(size_t)(dout0 + dl) * D_ + din0 + nl] = v;
    }
  } else {  // ---- wa: 4 rows per block ----
    const int wv = threadIdx.x >> 6, lane = threadIdx.x & 63;
    const int row = (bid - 64) * 4 + wv;
    const float* wr = W + (size_t)row * D_;
    float d1 = 0.f, d2 = 0.f;
#pragma unroll
    for (int p = 0; p < 8; ++p) {
      int c = lane + p * 64;
      float w = wr[c];
      d1 = fmaf(w, a1[c], d1);
      d2 = fmaf(w, a2[c], d2);
    }
#pragma unroll
    for (int off = 32; off > 0; off >>= 1) {
      d1 += __shfl_down(d1, off, 64);
      d2 += __shfl_down(d2, off, 64);
    }
    if (lane == 0) {
      wa1[row] = d1;
      wa2[row] = d2;
    }
  }
}

// ---------------------------------------------------------------------------
// k_scores_x: s1/s2 = X.wa1 / X.wa2 (fp32, exact-logit path) AND Xb = bf16(X)
// (same rounding point as in-kernel conversion -> numerics identical).
// NO graph pass here anymore: graph streams through k_attn's idle BW.
// ---------------------------------------------------------------------------
__global__ __launch_bounds__(256) void k_scores_x(const float* __restrict__ X,
                                                  const float* __restrict__ wa1,
                                                  const float* __restrict__ wa2,
                                                  float* __restrict__ s1,
                                                  float* __restrict__ s2,
                                                  bf16* __restrict__ Xb) {
  const int wv = threadIdx.x >> 6, lane = threadIdx.x & 63;
  const int r = blockIdx.x * 4 + wv;
  const float* x = X + (size_t)r * D_;
  float d1 = 0.f, d2 = 0.f;
#pragma unroll
  for (int p = 0; p < 2; ++p) {
    int c = lane * 4 + p * 256;
    float4 xv = *(const float4*)&x[c];
    float4 w1 = *(const float4*)&wa1[c];
    float4 w2 = *(const float4*)&wa2[c];
    d1 += xv.x * w1.x + xv.y * w1.y + xv.z * w1.z + xv.w * w1.w;
    d2 += xv.x * w2.x + xv.y * w2.y + xv.z * w2.z + xv.w * w2.w;
    bf16x4 h = {(bf16)xv.x, (bf16)xv.y, (bf16)xv.z, (bf16)xv.w};
    *(bf16x4*)&Xb[(size_t)r * D_ + c] = h;
  }
#pragma unroll
  for (int off = 32; off > 0; off >>= 1) {
    d1 += __shfl_down(d1, off, 64);
    d2 += __shfl_down(d2, off, 64);
  }
  if (lane == 0) {
    s1[r] = d1;
    s2[r] = d2;
  }
}

// ---------------------------------------------------------------------------
// k_hiddenT: HtB[frag] = Xb @ Wt^T. bf16 BOTH operands (half staging traffic,
// no cvt VALU). BM=BN=128, BK=32, LDH-40 pad (no bank conflicts), depth-1
// register prefetch. (R3-round variant — its regression was the separate
// gpack dispatch, not this kernel.)
// ---------------------------------------------------------------------------
#define LDH 40

__global__ __launch_bounds__(256, 2) void k_hiddenT(const bf16* __restrict__ Xb,
                                                    const bf16* __restrict__ Wt,
                                                    bf16* __restrict__ HtB) {
  __shared__ bf16 As[128][LDH];
  __shared__ bf16 Bs[128][LDH];
  const int t = threadIdx.x;
  const int m0 = blockIdx.y * 128;
  const int n0 = blockIdx.x * 128;
  const int lane = t & 63, w = t >> 6;
  const int wm = w >> 1, wn = w & 1;
  const int l15 = lane & 15, q = lane >> 4;

  f32x4 acc[4][4];
#pragma unroll
  for (int i = 0; i < 4; ++i)
#pragma unroll
    for (int j = 0; j < 4; ++j) acc[i][j] = (f32x4){0.f, 0.f, 0.f, 0.f};

  bf16x8 av[2], bv[2];
#pragma unroll
  for (int p = 0; p < 2; ++p) {
    int s = t + p * 256;
    av[p] = *(const bf16x8*)&Wt[(size_t)(m0 + (s >> 2)) * D_ + (s & 3) * 8];
    bv[p] = *(const bf16x8*)&Xb[(size_t)(n0 + (s >> 2)) * D_ + (s & 3) * 8];
  }

  for (int k0 = 0; k0 < D_; k0 += 32) {
    __syncthreads();
#pragma unroll
    for (int p = 0; p < 2; ++p) {
      int s = t + p * 256;
      *(bf16x8*)&As[s >> 2][(s & 3) * 8] = av[p];
      *(bf16x8*)&Bs[s >> 2][(s & 3) * 8] = bv[p];
    }
    __syncthreads();
    if (k0 + 32 < D_) {
#pragma unroll
      for (int p = 0; p < 2; ++p) {
        int s = t + p * 256;
        av[p] = *(const bf16x8*)&Wt[(size_t)(m0 + (s >> 2)) * D_ + k0 + 32 + (s & 3) * 8];
        bv[p] = *(const bf16x8*)&Xb[(size_t)(n0 + (s >> 2)) * D_ + k0 + 32 + (s & 3) * 8];
      }
    }
    bf16x8 a[4], bb[4];
#pragma unroll
    for (int i = 0; i < 4; ++i)
      a[i] = *(const bf16x8*)&As[wm * 64 + i * 16 + l15][q * 8];
#pragma unroll
    for (int j = 0; j < 4; ++j)
      bb[j] = *(const bf16x8*)&Bs[wn * 64 + j * 16 + l15][q * 8];
#pragma unroll
    for (int i = 0; i < 4; ++i)
#pragma unroll
      for (int j = 0; j < 4; ++j)
        acc[i][j] =
            __builtin_amdgcn_mfma_f32_16x16x32_bf16(a[i], bb[j], acc[i][j], 0, 0, 0);
  }
#pragma unroll
  for (int i = 0; i < 4; ++i)
#pragma unroll
    for (int r = 0; r < 4; ++r) {
      int dout = m0 + wm * 64 + i * 16 + q * 4 + r;
#pragma unroll
      for (int j = 0; j < 4; ++j) {
        int row = n0 + wn * 64 + j * 16 + l15;
        int bb_ = row >> 11;
        int jj = row & (N_ - 1);
        size_t addr = (size_t)bb_ * HTB_BATCH +
                      ((size_t)((dout >> 5) * (N_ / 16) + (jj >> 4)) * 64 +
                       ((jj >> 3) & 1) * 32 + (dout & 31)) *
                          8 +
                      (jj & 7);
        HtB[addr] = (bf16)acc[i][j][r];
      }
    }
}

// ---------------------------------------------------------------------------
// k_attn v9: d-split counted-vmcnt pipeline + DIRECT graph stream.
// Each block: 64 rows x 256 d, grid 512, 2 blocks/CU (~53 KB LDS).
// Graph int4 prefetched depth-2 into registers (gA/gB rotation, static
// indexing via 2x-unrolled body); its 134 MB HBM stream rides inside the
// pipeline stalls. vmcnt(3) = graph(it+2)[1] + stage(it+1)[2] in flight;
// stage(it) complete. setprio(1) around MFMA cluster (T5).
// ---------------------------------------------------------------------------
#define AT_BM 64
#define AT_BK 32
#define LDP 40
#define NIT (N_ / AT_BK)  // 64

#define ATTN_IT(IT, GCUR)                                                      \
  {                                                                            \
    const int it_ = (IT);                                                      \
    const int cur_ = it_ & 1;                                                  \
    /* issue graph load for it+2 (rotates into GCUR at end) */                 \
    int itn_ = it_ + 2;                                                        \
    int jg_ = (itn_ < NIT) ? itn_ * AT_BK : 0;                                 \
    int4 gnew_ = *(const int4*)&Gb[(size_t)pi * N_ + jg_ + pj];                \
    { /* P-compute from GCUR (4 values/thread) */                              \
      f32x4 sv = *(const f32x4*)&s2s[it_ * AT_BK + pj];                        \
      int gg[4] = {GCUR.x, GCUR.y, GCUR.z, GCUR.w};                            \
      float pv[4];                                                             \
      _Pragma("unroll") for (int q_ = 0; q_ < 4; ++q_) {                       \
        float e = s1r + sv[q_];                                                \
        e = (e > 0.f) ? e : NEG_ALPHA * e;                                     \
        pv[q_] = (gg[q_] != 0) ? __expf(e) : 0.f;                              \
        rsum += pv[q_];                                                        \
      }                                                                        \
      bf16x4 pb = {(bf16)pv[0], (bf16)pv[1], (bf16)pv[2], (bf16)pv[3]};        \
      *(bf16x4*)&Ps[cur_][pi][pj] = pb;                                        \
    }                                                                          \
    { /* issue stage for it+1 (wave-local, 2 gload_lds) */                     \
      const int jn_ = (it_ + 1 < NIT) ? it_ + 1 : 0;                           \
      _Pragma("unroll") for (int jo = 0; jo < 2; ++jo) {                       \
        const bf16* src =                                                      \
            &Hb[((size_t)dch * (N_ / 16) + jn_ * 2 + jo) * 512 + lane * 8];    \
        __builtin_amdgcn_global_load_lds(                                      \
            (const __attribute__((address_space(1))) void*)src,                \
            (__attribute__((address_space(3))) void*)                          \
                &HsF[(cur_ ^ 1) * 8192 + w * 1024 + jo * 512],                 \
            16, 0, 0);                                                         \
      }                                                                        \
    }                                                                          \
    asm volatile("s_waitcnt lgkmcnt(0)" ::: "memory");                         \
    __builtin_amdgcn_sched_barrier(0);                                         \
    __builtin_amdgcn_s_barrier();                                              \
    __builtin_amdgcn_sched_barrier(0);                                         \
    asm volatile("s_waitcnt vmcnt(3)" ::: "memory");                           \
    __builtin_amdgcn_sched_barrier(0);                                         \
    __builtin_amdgcn_s_setprio(1);                                             \
    _Pragma("unroll") for (int ks = 0; ks < 2; ++ks) {                         \
      const int ko = ks * 16 + hf * 8;                                         \
      bf16x8 a0 = *(const bf16x8*)&Ps[cur_][r31][ko];                          \
      bf16x8 a1 = *(const bf16x8*)&Ps[cur_][32 + r31][ko];                     \
      bf16x8 bB =                                                              \
          *(const bf16x8*)&HsF[cur_ * 8192 + w * 1024 + ks * 512 + lane * 8];  \
      acc[0] = __builtin_amdgcn_mfma_f32_32x32x16_bf16(a0, bB, acc[0], 0, 0, 0); \
      acc[1] = __builtin_amdgcn_mfma_f32_32x32x16_bf16(a1, bB, acc[1], 0, 0, 0); \
    }                                                                          \
    __builtin_amdgcn_s_setprio(0);                                             \
    GCUR = gnew_;                                                              \
  }

__global__ __launch_bounds__(512, 4) void k_attn(const bf16* __restrict__ HtB,
                                                 const int* __restrict__ graph,
                                                 const float* __restrict__ s1,
                                                 const float* __restrict__ s2,
                                                 float* __restrict__ out) {
  __shared__ __align__(16) bf16 Ps[2][AT_BM][LDP];  // 10,240 B
  __shared__ __align__(16) bf16 Hs[2][8192];        // 32,768 B
  __shared__ float s2s[N_];                         // 8 KB
  __shared__ float sum_part[AT_BM][8];              // 2 KB
  __shared__ float row_sum[AT_BM];

  const int t = threadIdx.x;
  const int bid = blockIdx.x;
  const int b = bid & 7;                     // XCD-affine: batch b -> XCD b
  const int i0 = ((bid >> 3) & 31) * AT_BM;  // row tile
  const int ds = bid >> 8;                   // d-half: 0 or 1
  const int lane = t & 63, w = t >> 6;
  const int r31 = lane & 31, hf = lane >> 5;
  const int dch = ds * 8 + w;  // this wave's 32-d chunk index

  const bf16* Hb = HtB + (size_t)b * HTB_BATCH;
  const int* Gb = graph + ((size_t)b * N_ + i0) * N_;

  for (int c = t; c < N_; c += 512) s2s[c] = s2[b * N_ + c];

  const int pi = t >> 3;
  const int c8 = t & 7;
  const int pj = c8 * 4;
  const float s1r = s1[b * N_ + i0 + pi];
  float rsum = 0.f;

  f32x16 acc[2];
#pragma unroll
  for (int i = 0; i < 2; ++i)
#pragma unroll
    for (int r = 0; r < 16; ++r) acc[i][r] = 0.f;

  // prologue: graph for it=0,1; stage it=0 (wave-local)
  int4 gA = *(const int4*)&Gb[(size_t)pi * N_ + pj];
  int4 gB = *(const int4*)&Gb[(size_t)pi * N_ + AT_BK + pj];
  bf16* HsF = &Hs[0][0];
#pragma unroll
  for (int jo = 0; jo < 2; ++jo) {
    const bf16* src = &Hb[((size_t)dch * (N_ / 16) + jo) * 512 + lane * 8];
    __builtin_amdgcn_global_load_lds(
        (const __attribute__((address_space(1))) void*)src,
        (__attribute__((address_space(3))) void*)&HsF[w * 1024 + jo * 512], 16,
        0, 0);
  }

  __syncthreads();  // s2s ready + prologue drained (vmcnt 0 at loop entry)

#pragma unroll 1
  for (int i2 = 0; i2 < NIT / 2; ++i2) {
    ATTN_IT(i2 * 2, gA);
    ATTN_IT(i2 * 2 + 1, gB);
  }

  sum_part[pi][c8] = rsum;
  __syncthreads();
  if (t < AT_BM) {
    float s = 0.f;
#pragma unroll
    for (int k = 0; k < 8; ++k) s += sum_part[t][k];
    row_sum[t] = s;
  }
  __syncthreads();

  // epilogue: normalize + elu + store (this block's d-half only)
  // C/D layout (32x32): col = lane&31, row = (r&3) + 8*(r>>2) + 4*hf
#pragma unroll
  for (int mt = 0; mt < 2; ++mt) {
    float inv[16];
#pragma unroll
    for (int r = 0; r < 16; ++r)
      inv[r] = 1.f / row_sum[mt * 32 + (r & 3) + 8 * (r >> 2) + 4 * hf];
    const int d = ds * 256 + w * 32 + r31;
#pragma unroll
    for (int r = 0; r < 16; ++r) {
      int i = mt * 32 + (r & 3) + 8 * (r >> 2) + 4 * hf;
      float x = acc[mt][r] * inv[r];
      out[((size_t)b * N_ + i0 + i) * D_ + d] = (x > 0.f) ? x : (__expf(x) - 1.f);
    }
  }
}

// ---------------------------------------------------------------------------
extern "C" void kernel_launch(void* const* d_in, const int* in_sizes, int n_in,
                              void* d_out, int out_size, void* d_ws,
                              size_t ws_size, hipStream_t stream) {
  const float* X = (const float*)d_in[0];
  const int* graph = (const int*)d_in[1];
  const float* W = (const float*)d_in[2];
  const float* a1 = (const float*)d_in[3];
  const float* a2 = (const float*)d_in[4];
  float* out = (float*)d_out;

  char* ws = (char*)d_ws;
  bf16* Wt = (bf16*)ws;                             // 0.5 MB
  bf16* HtB = (bf16*)(ws + (1 << 19));              // 16 MB
  bf16* Xb = (bf16*)(ws + (1 << 19) + (16 << 20));  // 16 MB
  float* s1 = (float*)(ws + (1 << 19) + (32 << 20));
  float* s2 = s1 + NROWS;
  float* wa1 = s2 + NROWS;
  float* wa2 = wa1 + D_;

  hipLaunchKernelGGL(k_pre0, dim3(192), dim3(256), 0, stream, W, Wt, a1, a2,
                     wa1, wa2);
  hipLaunchKernelGGL(k_scores_x, dim3(NROWS / 4), dim3(256), 0, stream, X, wa1,
                     wa2, s1, s2, Xb);
  hipLaunchKernelGGL(k_hiddenT, dim3(NROWS / 128, D_ / 128), dim3(256), 0,
                     stream, Xb, Wt, HtB);
  hipLaunchKernelGGL(k_attn, dim3(N_ / AT_BM * B_ * 2), dim3(512), 0, stream,
                     HtB, graph, s1, s2, out);
}